// Round 2
// 467.492 us; speedup vs baseline: 1.0838x; 1.0838x over previous
//
#include <hip/hip_runtime.h>
#include <hip/hip_bf16.h>
#include <stdint.h>

// ---- constants for this problem ----
// B=4, S=4096, D=1024, M=4096. DECAY=0.9
#define BSZ 4
#define SEQ 4096
#define DIM 1024
#define MDIM 4096
#define DECAYF 0.9f
#define OMD 0.1f
#define CHUNK 128
#define NCHUNK 32           // SEQ / CHUNK
#define DECAY_CHUNK 1.3901844577868923e-06f  // 0.9^128

typedef __bf16 bf16_t;
typedef __bf16 bf16x8 __attribute__((ext_vector_type(8)));
typedef __bf16 bf16x4 __attribute__((ext_vector_type(4)));
typedef float floatx4 __attribute__((ext_vector_type(4)));

// ---- async global->LDS, 16B per lane. lds ptr must be wave-uniform base;
//      HW writes lane i at base + i*16 (m97 pattern). ----
__device__ __forceinline__ void load16_lds(const void* g, void* l) {
  __builtin_amdgcn_global_load_lds(
      (__attribute__((address_space(1))) void*)g,
      (__attribute__((address_space(3))) void*)l,
      16, 0, 0);
}

// raw barrier (no vmcnt(0) drain, unlike __syncthreads), bracketed with
// compiler memory fences so no LDS read/DMA can be code-motioned across or
// into the barrier from either side.
#define BARRIER_MEM()              \
  do {                             \
    asm volatile("" ::: "memory"); \
    __builtin_amdgcn_s_barrier();  \
    asm volatile("" ::: "memory"); \
  } while (0)

// ---------------- scan kernels (unchanged, proven) ----------------
__global__ void scan_chunk_kernel(const float* __restrict__ x,
                                  float* __restrict__ chunk_end) {
  int t = blockIdx.x * 256 + threadIdx.x;
  int d = t & (DIM - 1);
  int c = (t >> 10) & (NCHUNK - 1);
  int b = t >> 15;
  const float* xp = x + ((size_t)(b * SEQ + c * CHUNK + 64)) * DIM + d;
  float p = 0.f;
#pragma unroll 8
  for (int s = 0; s < 64; ++s) p = DECAYF * p + OMD * xp[(size_t)s * DIM];
  chunk_end[t] = p;
}

__global__ void scan_carry_kernel(const float* __restrict__ chunk_end,
                                  float* __restrict__ carry_in,
                                  float* __restrict__ final_state) {
  int t = blockIdx.x * 256 + threadIdx.x;
  int d = t & (DIM - 1);
  int b = t >> 10;
  float carry = 0.f;
#pragma unroll
  for (int c = 0; c < NCHUNK; ++c) {
    int idx = (b * NCHUNK + c) * DIM + d;
    carry_in[idx] = carry;
    carry = carry * DECAY_CHUNK + chunk_end[idx];
  }
  final_state[t] = carry;  // == current_states[b, S-1, d]
}

__global__ void scan_emit_kernel(const float* __restrict__ x,
                                 const float* __restrict__ carry_in,
                                 bf16_t* __restrict__ prev) {
  int t = blockIdx.x * 256 + threadIdx.x;
  int d = t & (DIM - 1);
  int c = (t >> 10) & (NCHUNK - 1);
  int b = t >> 15;
  size_t base = ((size_t)(b * SEQ + c * CHUNK)) * DIM + d;
  const float* xp = x + base;
  bf16_t* pp = prev + base;
  float cs = carry_in[t];  // == current_states[b, c*CHUNK - 1, d]
#pragma unroll 4
  for (int s = 0; s < CHUNK; ++s) {
    pp[(size_t)s * DIM] = (bf16_t)cs;   // prev[t] = cs[t-1]
    cs = DECAYF * cs + OMD * xp[(size_t)s * DIM];
  }
}

// ---------------- fp32 -> bf16 convert (4 elems / thread) ----------------
__global__ void cvt_bf16_kernel(const float* __restrict__ w, bf16_t* __restrict__ o) {
  int t = blockIdx.x * 256 + threadIdx.x;
  float4 v = ((const float4*)w)[t];
  bf16x4 r = { (bf16_t)v.x, (bf16_t)v.y, (bf16_t)v.z, (bf16_t)v.w };
  ((bf16x4*)o)[t] = r;
}

// ---------------- GEMM: C[M][N] = A[M][K] * B[N][K]^T  (K-contiguous bf16)
// 256x256 tile, BK=64, 512 threads (8 waves, 2Mx4N, each 128x64 of C),
// 8-phase-per-K-tile-pair schedule (m201 template): per K-tile, 4 quadrant
// phases of 16 MFMA, raw s_barrier pairs (no vmcnt(0) drain), setprio(1)
// around each MFMA cluster (T5), counted boundary wait vmcnt(6) (T4).
//
// LDS layout: linear row-major [256 rows][64 cols] bf16 per operand buffer
// (row stride 128B), as required by global_load_lds (wave-uniform dest +
// lane*16). Bank-conflict-free swizzle: col-byte bits 4-6 ^= row bits 1-3
// (full 3-bit XOR -> each 16-lane quarter-wave of a ds_read_b128 covers all
// 32 banks, 2 lanes/bank = free). Realized as pre-swizzled GLOBAL source
// column on the write side + same XOR folded into read addresses (rule #21).
//
// vmcnt ledger (steady state, entering tile t): 6 in flight = (t+1).{A0,A1,B0}.
//   phase 1: +2 (t+1).B1 -> other buf     (region idle: read 2 phases ago)
//   phase 3: +4 (t+2).A  -> cur buf       (A reads done at phase-2 barrier)
//   phase 4: +2 (t+2).B0 -> cur buf       (B0 reads done at phase-2 barrier)
//   boundary: vmcnt(6) -> all of tile t+1 landed; (t+2) stays in flight.
#define READ_A(dst, CA, MH)                                                    \
  _Pragma("unroll") for (int i_ = 0; i_ < 4; ++i_)                             \
      _Pragma("unroll") for (int k_ = 0; k_ < 2; ++k_)                         \
          dst[i_][k_] = *(const bf16x8*)((const char*)(CA) + wrBase +          \
                                         (MH) * 8192 + i_ * 2048 + rbase +     \
                                         ((k_ * 64 + kc) ^ lswz));

#define READ_B(dst, CB, NH)                                                    \
  _Pragma("unroll") for (int j_ = 0; j_ < 2; ++j_)                             \
      _Pragma("unroll") for (int k_ = 0; k_ < 2; ++k_)                         \
          dst[j_][k_] = *(const bf16x8*)((const char*)(CB) + wcBase +          \
                                         (NH) * 4096 + j_ * 2048 + rbase +     \
                                         ((k_ * 64 + kc) ^ lswz));

#define MMQ(AF, BF, MO, NO)                                                    \
  _Pragma("unroll") for (int k_ = 0; k_ < 2; ++k_)                             \
      _Pragma("unroll") for (int i_ = 0; i_ < 4; ++i_)                         \
          _Pragma("unroll") for (int j_ = 0; j_ < 2; ++j_)                     \
              acc[(MO) + i_][(NO) + j_] =                                      \
                  __builtin_amdgcn_mfma_f32_16x16x32_bf16(                     \
                      AF[i_][k_], BF[j_][k_], acc[(MO) + i_][(NO) + j_],       \
                      0, 0, 0);

template <int N, int K, int MT, int EPI>
__global__ __launch_bounds__(512, 2) void gemm256_kernel(
    const bf16_t* __restrict__ A, const bf16_t* __restrict__ B,
    void* __restrict__ Cout, const float* __restrict__ X,
    float* __restrict__ loss_acc) {
  constexpr int NT = N / 256;
  constexpr int NTK = K / 64;
  static_assert((NTK & 1) == 0 && NTK >= 4, "even K-tile count");
  static_assert(MT % 8 == 0, "m-tiles divisible by XCD count");
  __shared__ __attribute__((aligned(16))) bf16_t sA[2][16384];  // 2 x 32KB
  __shared__ __attribute__((aligned(16))) bf16_t sB[2][16384];  // 2 x 32KB

  const int tid = threadIdx.x;
  const int wave = tid >> 6;
  const int lane = tid & 63;
  const int bid = blockIdx.x;
  const int xcd = bid & 7;
  const int slot = bid >> 3;
  const int tm = (xcd * (MT / 8) + slot / NT) * 256;
  const int tn = (slot % NT) * 256;
  const int wr = wave >> 2;                 // 0..1 : wave row (128 C-rows)
  const int wc = wave & 3;                  // 0..3 : wave col (64 C-cols)
  const int wrBase = wr * 16384;            // byte base of wave's A rows
  const int wcBase = wc * 8192;             // byte base of wave's B rows
  // read-side: fragment row R has bits1-3 == (lane&15) bits1-3; col-byte
  // c = k*64 + (lane>>4)*16 is fetched from LDS col c ^ ((R>>1)&7)<<4.
  const int rbase = (lane & 15) * 128;
  const int kc = (lane >> 4) * 16;
  const int lswz = ((lane >> 1) & 7) << 4;
  // stage-side: LDS linear (DMA), global source column pre-swizzled with the
  // same XOR. staged row srow = wave*8 + lane>>3 (srow+64 for 2nd load has
  // identical bits1-3, so one scolb serves both).
  const int srow = wave * 8 + (lane >> 3);
  const int scolb = ((lane & 7) * 16) ^ (((srow >> 1) & 7) << 4);

  floatx4 acc[8][4];
#pragma unroll
  for (int i = 0; i < 8; ++i)
#pragma unroll
    for (int j = 0; j < 4; ++j) acc[i][j] = (floatx4){0.f, 0.f, 0.f, 0.f};

  // stage one half-tile (128 rows x 64 cols of one operand) = 2 DMA / thread
  auto stage_ht = [&](const bf16_t* G, int tb, bf16_t* lbuf, int kt, int h) {
    char* lbase = (char*)lbuf + h * 16384 + wave * 1024;
    const char* gbase =
        (const char*)G + ((size_t)(tb + h * 128 + srow) * K + kt) * 2 + scolb;
    load16_lds(gbase, lbase);                              // rows r+0..63
    load16_lds(gbase + (size_t)64 * K * 2, lbase + 8192);  // rows r+64..127
  };

  auto tile4 = [&](int t, bf16_t* cA, bf16_t* cB, bf16_t* nB) {
    bf16x8 a0[4][2], a1[4][2], b0[2][2], b1[2][2];
    const int kt2 = (t + 2) * 64;
    // ---- phase 1: quadrant (Alo, Blo)
    READ_A(a0, cA, 0);
    READ_B(b0, cB, 0);
    if (t + 1 < NTK) stage_ht(B, tn, nB, (t + 1) * 64, 1);
    BARRIER_MEM();
    __builtin_amdgcn_s_setprio(1);
    MMQ(a0, b0, 0, 0);
    __builtin_amdgcn_s_setprio(0);
    BARRIER_MEM();
    // ---- phase 2: quadrant (Ahi, Blo)
    READ_A(a1, cA, 1);
    BARRIER_MEM();
    __builtin_amdgcn_s_setprio(1);
    MMQ(a1, b0, 4, 0);
    __builtin_amdgcn_s_setprio(0);
    BARRIER_MEM();
    // ---- phase 3: quadrant (Ahi, Bhi); cur-A reads all retired -> stage t+2.A
    READ_B(b1, cB, 1);
    if (t + 2 < NTK) {
      stage_ht(A, tm, cA, kt2, 0);
      stage_ht(A, tm, cA, kt2, 1);
    }
    BARRIER_MEM();
    __builtin_amdgcn_s_setprio(1);
    MMQ(a1, b1, 4, 2);
    __builtin_amdgcn_s_setprio(0);
    BARRIER_MEM();
    // ---- phase 4: quadrant (Alo, Bhi); cur-B0 reads retired -> stage t+2.B0
    if (t + 2 < NTK) stage_ht(B, tn, cB, kt2, 0);
    BARRIER_MEM();
    __builtin_amdgcn_s_setprio(1);
    MMQ(a0, b1, 0, 2);
    __builtin_amdgcn_s_setprio(0);
    // tile boundary: tile t+1 must be fully landed; the 6 newest loads
    // ((t+2).A0,A1,B0) may stay in flight. Never vmcnt(0) mid-loop (T4).
    if (t + 1 < NTK) {
      if (t + 2 < NTK) asm volatile("s_waitcnt vmcnt(6)" ::: "memory");
      else             asm volatile("s_waitcnt vmcnt(0)" ::: "memory");
    }
    BARRIER_MEM();
  };

  // prologue: tile0 fully + tile1.{A0,A1,B0} (14 loads); vmcnt(6) -> tile0
  // landed, 6 loads (tile1.A0,A1,B0) in flight = steady-state precondition.
  stage_ht(A, tm, sA[0], 0, 0);
  stage_ht(A, tm, sA[0], 0, 1);
  stage_ht(B, tn, sB[0], 0, 0);
  stage_ht(B, tn, sB[0], 0, 1);
  stage_ht(A, tm, sA[1], 64, 0);
  stage_ht(A, tm, sA[1], 64, 1);
  stage_ht(B, tn, sB[1], 64, 0);
  asm volatile("s_waitcnt vmcnt(6)" ::: "memory");
  BARRIER_MEM();

#pragma unroll 1
  for (int t = 0; t < NTK; t += 2) {
    tile4(t, sA[0], sB[0], sB[1]);
    tile4(t + 1, sA[1], sB[1], sB[0]);
  }

  // epilogue. C/D frag: col = lane&15, row = (lane>>4)*4 + reg
  const int r0 = (lane >> 4) * 4;
  const int cn = lane & 15;
  if constexpr (EPI == 0) {
    bf16_t* H = (bf16_t*)Cout;
#pragma unroll
    for (int i = 0; i < 8; ++i)
#pragma unroll
      for (int j = 0; j < 4; ++j)
#pragma unroll
        for (int r = 0; r < 4; ++r) {
          int m = tm + wr * 128 + i * 16 + r0 + r;
          int n = tn + wc * 64 + j * 16 + cn;
          float v = acc[i][j][r];
          v = v / (1.f + __expf(-v));  // silu
          H[(size_t)m * N + n] = (bf16_t)v;
        }
  } else {
    float* O = (float*)Cout;
    float ls = 0.f;
#pragma unroll
    for (int i = 0; i < 8; ++i)
#pragma unroll
      for (int j = 0; j < 4; ++j)
#pragma unroll
        for (int r = 0; r < 4; ++r) {
          int m = tm + wr * 128 + i * 16 + r0 + r;
          int n = tn + wc * 64 + j * 16 + cn;
          size_t off = (size_t)m * N + n;
          float v = acc[i][j][r];
          O[off] = v;
          float dd = v - X[off];
          ls += dd * dd;
        }
    // wave reduction then one atomic per wave
#pragma unroll
    for (int s = 32; s > 0; s >>= 1) ls += __shfl_down(ls, s, 64);
    if (lane == 0) atomicAdd(loss_acc, ls);
  }
}

#undef READ_A
#undef READ_B
#undef MMQ

__global__ void finalize_loss_kernel(const float* __restrict__ loss_acc,
                                     float* __restrict__ out) {
  if (threadIdx.x == 0)
    out[0] = loss_acc[0] * (1.0f / (float)(BSZ * SEQ * DIM));
}

// ---------------- launch ----------------
extern "C" void kernel_launch(void* const* d_in, const int* in_sizes, int n_in,
                              void* d_out, int out_size, void* d_ws, size_t ws_size,
                              hipStream_t stream) {
  const float* x  = (const float*)d_in[0];   // [4][4096][1024]
  const float* w1 = (const float*)d_in[1];   // [4096][1024]
  const float* w2 = (const float*)d_in[2];   // [1024][4096]
  float* out = (float*)d_out;                // mem_out | loss | final_state

  const int BT = BSZ * SEQ;                  // 16384 rows, 64 m-tiles of 256
  char* ws = (char*)d_ws;
  // workspace layout (bytes)
  bf16_t* prev      = (bf16_t*)(ws);                      // 16M bf16  = 33,554,432 B
  bf16_t* h         = (bf16_t*)(ws + 33554432ull);        // 64M bf16  = 134,217,728 B
  bf16_t* w1b       = (bf16_t*)(ws + 167772160ull);       // 4M bf16   = 8,388,608 B
  bf16_t* w2b       = (bf16_t*)(ws + 176160768ull);       // 4M bf16   = 8,388,608 B
  float*  chunk_end = (float*)(ws + 184549376ull);        // 128K f32  = 524,288 B
  float*  carry_in  = (float*)(ws + 185073664ull);        // 128K f32  = 524,288 B
  float*  loss_acc  = (float*)(ws + 185597952ull);        // 4 B

  hipMemsetAsync(loss_acc, 0, sizeof(float), stream);

  // weights -> bf16 (4,194,304 elems each; 4/thread)
  cvt_bf16_kernel<<<4096, 256, 0, stream>>>(w1, w1b);
  cvt_bf16_kernel<<<4096, 256, 0, stream>>>(w2, w2b);

  // chunked EMA scan -> prev states (bf16) + final_state (fp32, d_out tail)
  scan_chunk_kernel<<<(BSZ * NCHUNK * DIM) / 256, 256, 0, stream>>>(x, chunk_end);
  scan_carry_kernel<<<(BSZ * DIM) / 256, 256, 0, stream>>>(chunk_end, carry_in,
                                                           out + 16777217);
  scan_emit_kernel<<<(BSZ * NCHUNK * DIM) / 256, 256, 0, stream>>>(x, carry_in, prev);

  // h = silu(prev @ w1^T)  : [16384 x 1024] x [4096 x 1024]^T -> bf16 [16384 x 4096]
  gemm256_kernel<MDIM, DIM, BT / 256, 0>
      <<<(BT / 256) * (MDIM / 256), 512, 0, stream>>>(prev, w1b, h, nullptr, nullptr);

  // mem_out = h @ w2^T : [16384 x 4096] x [1024 x 4096]^T -> fp32 [16384 x 1024]
  // fused: loss partial sums vs x
  gemm256_kernel<DIM, MDIM, BT / 256, 1>
      <<<(BT / 256) * (DIM / 256), 512, 0, stream>>>(h, w2b, out, x, loss_acc);

  finalize_loss_kernel<<<1, 64, 0, stream>>>(loss_acc, out + 16777216);
}

// Round 5
// 461.296 us; speedup vs baseline: 1.0984x; 1.0134x over previous
//
#include <hip/hip_runtime.h>
#include <hip/hip_bf16.h>
#include <stdint.h>

// ---- constants for this problem ----
// B=4, S=4096, D=1024, M=4096. DECAY=0.9
#define BSZ 4
#define SEQ 4096
#define DIM 1024
#define MDIM 4096
#define DECAYF 0.9f
#define OMD 0.1f
#define CHUNK 128
#define NCHUNK 32           // SEQ / CHUNK
#define DECAY_CHUNK 1.3901844577868923e-06f  // 0.9^128

typedef __bf16 bf16_t;
typedef __bf16 bf16x8 __attribute__((ext_vector_type(8)));
typedef __bf16 bf16x4 __attribute__((ext_vector_type(4)));
typedef float floatx4 __attribute__((ext_vector_type(4)));

// ---- async global->LDS, 16B per lane. lds ptr must be wave-uniform base;
//      HW writes lane i at base + i*16 (m97 pattern). ----
__device__ __forceinline__ void load16_lds(const void* g, void* l) {
  __builtin_amdgcn_global_load_lds(
      (__attribute__((address_space(1))) void*)g,
      (__attribute__((address_space(3))) void*)l,
      16, 0, 0);
}

// R9 hybrid: R8's 8-phase schedule, but "memory"-clobbered barriers kept at
// exactly the two DATA-CRITICAL points per K-tile (R7-v2's proven-passing
// mechanism), bare s_barrier everywhere else:
//   - end of phase 2: licenses phase-3 DMA overwrite of cur-A (last reader
//     of cur-A retires there). Forced vmcnt(0) drains only (t+1).B1, issued
//     one full MFMA phase earlier -> mostly covered.
//   - tile boundary: licenses next tile's reads. Forced vmcnt(0) drains
//     (t+2).{A0,A1,B0}, issued 1-2 phases earlier -> partially covered.
// The other 8 barriers/K-tile are bare (no drain) -> pipeline holds.
// Rule #18: clobber-free waits are pinned with sched_barrier(0).
#define SB()  __builtin_amdgcn_sched_barrier(0)
#define BAR() __builtin_amdgcn_s_barrier()
#define WAIT_LGKM0() do { asm volatile("s_waitcnt lgkmcnt(0)"); SB(); } while (0)
#define BARRIER_MEM()              \
  do {                             \
    asm volatile("" ::: "memory"); \
    __builtin_amdgcn_s_barrier();  \
    asm volatile("" ::: "memory"); \
  } while (0)

// ---------------- scan kernels (unchanged, proven) ----------------
__global__ void scan_chunk_kernel(const float* __restrict__ x,
                                  float* __restrict__ chunk_end) {
  int t = blockIdx.x * 256 + threadIdx.x;
  int d = t & (DIM - 1);
  int c = (t >> 10) & (NCHUNK - 1);
  int b = t >> 15;
  const float* xp = x + ((size_t)(b * SEQ + c * CHUNK + 64)) * DIM + d;
  float p = 0.f;
#pragma unroll 8
  for (int s = 0; s < 64; ++s) p = DECAYF * p + OMD * xp[(size_t)s * DIM];
  chunk_end[t] = p;
}

__global__ void scan_carry_kernel(const float* __restrict__ chunk_end,
                                  float* __restrict__ carry_in,
                                  float* __restrict__ final_state) {
  int t = blockIdx.x * 256 + threadIdx.x;
  int d = t & (DIM - 1);
  int b = t >> 10;
  float carry = 0.f;
#pragma unroll
  for (int c = 0; c < NCHUNK; ++c) {
    int idx = (b * NCHUNK + c) * DIM + d;
    carry_in[idx] = carry;
    carry = carry * DECAY_CHUNK + chunk_end[idx];
  }
  final_state[t] = carry;  // == current_states[b, S-1, d]
}

__global__ void scan_emit_kernel(const float* __restrict__ x,
                                 const float* __restrict__ carry_in,
                                 bf16_t* __restrict__ prev) {
  int t = blockIdx.x * 256 + threadIdx.x;
  int d = t & (DIM - 1);
  int c = (t >> 10) & (NCHUNK - 1);
  int b = t >> 15;
  size_t base = ((size_t)(b * SEQ + c * CHUNK)) * DIM + d;
  const float* xp = x + base;
  bf16_t* pp = prev + base;
  float cs = carry_in[t];  // == current_states[b, c*CHUNK - 1, d]
#pragma unroll 4
  for (int s = 0; s < CHUNK; ++s) {
    pp[(size_t)s * DIM] = (bf16_t)cs;   // prev[t] = cs[t-1]
    cs = DECAYF * cs + OMD * xp[(size_t)s * DIM];
  }
}

// ---------------- fp32 -> bf16 convert (4 elems / thread) ----------------
__global__ void cvt_bf16_kernel(const float* __restrict__ w, bf16_t* __restrict__ o) {
  int t = blockIdx.x * 256 + threadIdx.x;
  float4 v = ((const float4*)w)[t];
  bf16x4 r = { (bf16_t)v.x, (bf16_t)v.y, (bf16_t)v.z, (bf16_t)v.w };
  ((bf16x4*)o)[t] = r;
}

// ---------------- GEMM: C[M][N] = A[M][K] * B[N][K]^T  (K-contiguous bf16)
// 256x256 tile, BK=64, 512 threads (8 waves, 2Mx4N, each 128x64 of C),
// 4 quadrant phases of 16 MFMA per K-tile; setprio(1) around MFMA (T5).
//
// LDS: linear row-major [256][64] bf16 per operand buffer (row stride 128B),
// as global_load_lds requires. Conflict-free swizzle: col-byte bits 4-6 ^=
// row bits 1-3, realized as pre-swizzled GLOBAL source column on the write
// side + same XOR folded into read addresses (rule #21). Refcheck'd in R2.
//
// vmcnt ledger (steady state, entering tile t): 6 in flight = (t+1).{A0,A1,B0}
// (0 when boundary clobber drains; ledger is then an upper bound -- correct).
//   phase 1: +2 (t+1).B1 -> other buf     (region idle: read 2 phases ago)
//   phase 3: +4 (t+2).A  -> cur buf       (A reads done at clobbered p2 bar)
//   phase 4: +2 (t+2).B0 -> cur buf       (B0 reads done at phase-2 barrier)
#define READ_A(dst, CA, MH)                                                    \
  _Pragma("unroll") for (int i_ = 0; i_ < 4; ++i_)                             \
      _Pragma("unroll") for (int k_ = 0; k_ < 2; ++k_)                         \
          dst[i_][k_] = *(const bf16x8*)((const char*)(CA) + wrBase +          \
                                         (MH) * 8192 + i_ * 2048 + rbase +     \
                                         ((k_ * 64 + kc) ^ lswz));

#define READ_B(dst, CB, NH)                                                    \
  _Pragma("unroll") for (int j_ = 0; j_ < 2; ++j_)                             \
      _Pragma("unroll") for (int k_ = 0; k_ < 2; ++k_)                         \
          dst[j_][k_] = *(const bf16x8*)((const char*)(CB) + wcBase +          \
                                         (NH) * 4096 + j_ * 2048 + rbase +     \
                                         ((k_ * 64 + kc) ^ lswz));

#define MMQ(AF, BF, MO, NO)                                                    \
  _Pragma("unroll") for (int k_ = 0; k_ < 2; ++k_)                             \
      _Pragma("unroll") for (int i_ = 0; i_ < 4; ++i_)                         \
          _Pragma("unroll") for (int j_ = 0; j_ < 2; ++j_)                     \
              acc[(MO) + i_][(NO) + j_] =                                      \
                  __builtin_amdgcn_mfma_f32_16x16x32_bf16(                     \
                      AF[i_][k_], BF[j_][k_], acc[(MO) + i_][(NO) + j_],       \
                      0, 0, 0);

template <int N, int K, int MT, int EPI>
__global__ __launch_bounds__(512, 2) void gemm256_kernel(
    const bf16_t* __restrict__ A, const bf16_t* __restrict__ B,
    void* __restrict__ Cout, const float* __restrict__ X,
    float* __restrict__ loss_acc) {
  constexpr int NT = N / 256;
  constexpr int NTK = K / 64;
  static_assert((NTK & 1) == 0 && NTK >= 4, "even K-tile count");
  static_assert(MT % 8 == 0, "m-tiles divisible by XCD count");
  __shared__ __attribute__((aligned(16))) bf16_t sA[2][16384];  // 2 x 32KB
  __shared__ __attribute__((aligned(16))) bf16_t sB[2][16384];  // 2 x 32KB

  const int tid = threadIdx.x;
  const int wave = tid >> 6;
  const int lane = tid & 63;
  const int bid = blockIdx.x;
  const int xcd = bid & 7;
  const int slot = bid >> 3;
  const int tm = (xcd * (MT / 8) + slot / NT) * 256;
  const int tn = (slot % NT) * 256;
  const int wr = wave >> 2;                 // 0..1 : wave row (128 C-rows)
  const int wc = wave & 3;                  // 0..3 : wave col (64 C-cols)
  const int wrBase = wr * 16384;            // byte base of wave's A rows
  const int wcBase = wc * 8192;             // byte base of wave's B rows
  // read-side: fragment row R has bits1-3 == (lane&15) bits1-3; col-byte
  // c = k*64 + (lane>>4)*16 is fetched from LDS col c ^ ((R>>1)&7)<<4.
  const int rbase = (lane & 15) * 128;
  const int kc = (lane >> 4) * 16;
  const int lswz = ((lane >> 1) & 7) << 4;
  // stage-side: LDS linear (DMA), global source column pre-swizzled with the
  // same XOR. staged row srow = wave*8 + lane>>3 (srow+64 for 2nd load has
  // identical bits1-3, so one scolb serves both).
  const int srow = wave * 8 + (lane >> 3);
  const int scolb = ((lane & 7) * 16) ^ (((srow >> 1) & 7) << 4);

  floatx4 acc[8][4];
#pragma unroll
  for (int i = 0; i < 8; ++i)
#pragma unroll
    for (int j = 0; j < 4; ++j) acc[i][j] = (floatx4){0.f, 0.f, 0.f, 0.f};

  // stage one half-tile (128 rows x 64 cols of one operand) = 2 DMA / thread
  auto stage_ht = [&](const bf16_t* G, int tb, bf16_t* lbuf, int kt, int h) {
    char* lbase = (char*)lbuf + h * 16384 + wave * 1024;
    const char* gbase =
        (const char*)G + ((size_t)(tb + h * 128 + srow) * K + kt) * 2 + scolb;
    load16_lds(gbase, lbase);                              // rows r+0..63
    load16_lds(gbase + (size_t)64 * K * 2, lbase + 8192);  // rows r+64..127
  };

  auto tile4 = [&](int t, bf16_t* cA, bf16_t* cB, bf16_t* nB) {
    bf16x8 a0[4][2], a1[4][2], b0[2][2], b1[2][2];
    const int kt2 = (t + 2) * 64;
    // ---- phase 1: quadrant (Alo, Blo)
    READ_A(a0, cA, 0);
    READ_B(b0, cB, 0);
    if (t + 1 < NTK) stage_ht(B, tn, nB, (t + 1) * 64, 1);
    SB(); BAR();
    WAIT_LGKM0();
    __builtin_amdgcn_s_setprio(1);
    MMQ(a0, b0, 0, 0);
    __builtin_amdgcn_s_setprio(0);
    SB(); BAR();
    // ---- phase 2: quadrant (Ahi, Blo)
    READ_A(a1, cA, 1);
    SB(); BAR();
    WAIT_LGKM0();
    __builtin_amdgcn_s_setprio(1);
    MMQ(a1, b0, 4, 0);
    __builtin_amdgcn_s_setprio(0);
    // DATA-CRITICAL: all waves' reads of cur-A retire here; phase 3 DMA may
    // overwrite cur-A after this barrier. Clobbered (R7-v2 proven): forced
    // drain covers only (t+1).B1, issued one MFMA phase ago.
    BARRIER_MEM();
    // ---- phase 3: quadrant (Ahi, Bhi); cur-A region free -> stage t+2.A
    READ_B(b1, cB, 1);
    if (t + 2 < NTK) {
      stage_ht(A, tm, cA, kt2, 0);
      stage_ht(A, tm, cA, kt2, 1);
    }
    SB(); BAR();
    WAIT_LGKM0();
    __builtin_amdgcn_s_setprio(1);
    MMQ(a1, b1, 4, 2);
    __builtin_amdgcn_s_setprio(0);
    SB(); BAR();
    // ---- phase 4: quadrant (Alo, Bhi); cur-B0 reads retired -> stage t+2.B0
    if (t + 2 < NTK) stage_ht(B, tn, cB, kt2, 0);
    SB(); BAR();
    __builtin_amdgcn_s_setprio(1);
    MMQ(a0, b1, 0, 2);
    __builtin_amdgcn_s_setprio(0);
    SB();
    // tile boundary: tile t+1 must be fully landed before next tile's reads.
    // Counted wait (upper bound), then DATA-CRITICAL clobbered barrier
    // (forced drain covers (t+2).{A0,A1,B0}, issued 1-2 phases ago).
    if (t + 1 < NTK) { asm volatile("s_waitcnt vmcnt(6)"); SB(); }
    BARRIER_MEM();
  };

  // prologue: tile0 fully + tile1.{A0,A1,B0} (14 loads); one-time clobbered
  // barrier (drain cost negligible once per block).
  stage_ht(A, tm, sA[0], 0, 0);
  stage_ht(A, tm, sA[0], 0, 1);
  stage_ht(B, tn, sB[0], 0, 0);
  stage_ht(B, tn, sB[0], 0, 1);
  stage_ht(A, tm, sA[1], 64, 0);
  stage_ht(A, tm, sA[1], 64, 1);
  stage_ht(B, tn, sB[1], 64, 0);
  BARRIER_MEM();

#pragma unroll 1
  for (int t = 0; t < NTK; t += 2) {
    tile4(t, sA[0], sB[0], sB[1]);
    tile4(t + 1, sA[1], sB[1], sB[0]);
  }

  // epilogue. C/D frag: col = lane&15, row = (lane>>4)*4 + reg
  const int r0 = (lane >> 4) * 4;
  const int cn = lane & 15;
  if constexpr (EPI == 0) {
    bf16_t* H = (bf16_t*)Cout;
#pragma unroll
    for (int i = 0; i < 8; ++i)
#pragma unroll
      for (int j = 0; j < 4; ++j)
#pragma unroll
        for (int r = 0; r < 4; ++r) {
          int m = tm + wr * 128 + i * 16 + r0 + r;
          int n = tn + wc * 64 + j * 16 + cn;
          float v = acc[i][j][r];
          v = v / (1.f + __expf(-v));  // silu
          H[(size_t)m * N + n] = (bf16_t)v;
        }
  } else {
    float* O = (float*)Cout;
    float ls = 0.f;
#pragma unroll
    for (int i = 0; i < 8; ++i)
#pragma unroll
      for (int j = 0; j < 4; ++j)
#pragma unroll
        for (int r = 0; r < 4; ++r) {
          int m = tm + wr * 128 + i * 16 + r0 + r;
          int n = tn + wc * 64 + j * 16 + cn;
          size_t off = (size_t)m * N + n;
          float v = acc[i][j][r];
          O[off] = v;
          float dd = v - X[off];
          ls += dd * dd;
        }
    // wave reduction then one atomic per wave
#pragma unroll
    for (int s = 32; s > 0; s >>= 1) ls += __shfl_down(ls, s, 64);
    if (lane == 0) atomicAdd(loss_acc, ls);
  }
}

#undef READ_A
#undef READ_B
#undef MMQ

__global__ void finalize_loss_kernel(const float* __restrict__ loss_acc,
                                     float* __restrict__ out) {
  if (threadIdx.x == 0)
    out[0] = loss_acc[0] * (1.0f / (float)(BSZ * SEQ * DIM));
}

// ---------------- launch ----------------
extern "C" void kernel_launch(void* const* d_in, const int* in_sizes, int n_in,
                              void* d_out, int out_size, void* d_ws, size_t ws_size,
                              hipStream_t stream) {
  const float* x  = (const float*)d_in[0];   // [4][4096][1024]
  const float* w1 = (const float*)d_in[1];   // [4096][1024]
  const float* w2 = (const float*)d_in[2];   // [1024][4096]
  float* out = (float*)d_out;                // mem_out | loss | final_state

  const int BT = BSZ * SEQ;                  // 16384 rows, 64 m-tiles of 256
  char* ws = (char*)d_ws;
  // workspace layout (bytes)
  bf16_t* prev      = (bf16_t*)(ws);                      // 16M bf16  = 33,554,432 B
  bf16_t* h         = (bf16_t*)(ws + 33554432ull);        // 64M bf16  = 134,217,728 B
  bf16_t* w1b       = (bf16_t*)(ws + 167772160ull);       // 4M bf16   = 8,388,608 B
  bf16_t* w2b       = (bf16_t*)(ws + 176160768ull);       // 4M bf16   = 8,388,608 B
  float*  chunk_end = (float*)(ws + 184549376ull);        // 128K f32  = 524,288 B
  float*  carry_in  = (float*)(ws + 185073664ull);        // 128K f32  = 524,288 B
  float*  loss_acc  = (float*)(ws + 185597952ull);        // 4 B

  hipMemsetAsync(loss_acc, 0, sizeof(float), stream);

  // weights -> bf16 (4,194,304 elems each; 4/thread)
  cvt_bf16_kernel<<<4096, 256, 0, stream>>>(w1, w1b);
  cvt_bf16_kernel<<<4096, 256, 0, stream>>>(w2, w2b);

  // chunked EMA scan -> prev states (bf16) + final_state (fp32, d_out tail)
  scan_chunk_kernel<<<(BSZ * NCHUNK * DIM) / 256, 256, 0, stream>>>(x, chunk_end);
  scan_carry_kernel<<<(BSZ * DIM) / 256, 256, 0, stream>>>(chunk_end, carry_in,
                                                           out + 16777217);
  scan_emit_kernel<<<(BSZ * NCHUNK * DIM) / 256, 256, 0, stream>>>(x, carry_in, prev);

  // h = silu(prev @ w1^T)  : [16384 x 1024] x [4096 x 1024]^T -> bf16 [16384 x 4096]
  gemm256_kernel<MDIM, DIM, BT / 256, 0>
      <<<(BT / 256) * (MDIM / 256), 512, 0, stream>>>(prev, w1b, h, nullptr, nullptr);

  // mem_out = h @ w2^T : [16384 x 4096] x [1024 x 4096]^T -> fp32 [16384 x 1024]
  // fused: loss partial sums vs x
  gemm256_kernel<DIM, MDIM, BT / 256, 1>
      <<<(BT / 256) * (DIM / 256), 512, 0, stream>>>(h, w2b, out, x, loss_acc);

  finalize_loss_kernel<<<1, 64, 0, stream>>>(loss_acc, out + 16777216);
}